// Round 7
// baseline (199.738 us; speedup 1.0000x reference)
//
#include <hip/hip_runtime.h>
#include <hip/hip_bf16.h>
#include <math.h>

#define NB 128   // batch
#define NR 36    // regions
#define NW 32    // words
#define ND 256   // feature dim

#define MARGINf 0.05f
#define TEMPf   14.0f
#define LAMf    9.0f
#define EPSf    1e-8f

typedef _Float16 f16x8 __attribute__((ext_vector_type(8)));
typedef _Float16 f16x4 __attribute__((ext_vector_type(4)));
typedef float    f32x4 __attribute__((ext_vector_type(4)));

// ================= workspace layout (float offsets) =================
#define WS_SCORES 0
#define WS_N1     16384
#define WS_GH     20480                  // f16[128][48*72] rows/cols >=36 zero
#define GH_ELEMS  (48 * 72)              // 3456 f16 per image
#define WS_IMH    241664                 // f16[128][48][256], rows 36..47 zero
#define WS_SH     1028096                // f16[128][32][256], word-masked
#define WS_NEED_BYTES ((size_t)1552384 * 4)   // ~6.2 MB

// ================= fallback workspace layout =================
#define G_STRIDE  40
#define FB_WS_G   (NB * NB)
#define FB_WS_N1  (FB_WS_G + NB * NR * G_STRIDE)
#define HS 264

// =====================================================================
// prep3: f16 conversions (imh zero-padded, sh word-masked), Gram f16, n1
// =====================================================================
__global__ __launch_bounds__(256) void prep3_kernel(
    const float* __restrict__ im, const float* __restrict__ s,
    const int* __restrict__ s_l, float* __restrict__ ws)
{
    const int b = blockIdx.x;
    const int t = threadIdx.x;
    __shared__ float s_imf[NR * 260];

    const float4* im4 = (const float4*)(im + (size_t)b * NR * ND);
    for (int i = t; i < NR * 64; i += 256) {
        int r = i >> 6, c4 = i & 63;
        *(float4*)&s_imf[r * 260 + 4 * c4] = im4[i];
    }
    // zero G region (1728 u32)
    unsigned int* Gz = (unsigned int*)((_Float16*)(ws + WS_GH) + (size_t)b * GH_ELEMS);
    for (int i = t; i < GH_ELEMS / 2; i += 256) Gz[i] = 0u;
    __syncthreads();

    // Gram f16 [48][72], fill 36x36
    _Float16* Gh = (_Float16*)(ws + WS_GH) + (size_t)b * GH_ELEMS;
    for (int i = t; i < NR * NR; i += 256) {
        int r = i / NR, rp = i - r * NR;
        const float4* a  = (const float4*)&s_imf[r * 260];
        const float4* bb = (const float4*)&s_imf[rp * 260];
        float acc = 0.f;
        for (int k = 0; k < 64; ++k) {
            float4 x = a[k], y = bb[k];
            acc += x.x * y.x + x.y * y.y + x.z * y.z + x.w * y.w;
        }
        Gh[r * 72 + rp] = (_Float16)acc;
    }

    // imh f16 [48][256], rows 36..47 zero
    _Float16* imh = (_Float16*)(ws + WS_IMH) + (size_t)b * 48 * 256;
    for (int i = t; i < 48 * 32; i += 256) {
        int r = i >> 5, ch = i & 31;
        f16x8 h;
        if (r < NR) {
            const float4 a  = *(const float4*)&s_imf[r * 260 + ch * 8];
            const float4 bb = *(const float4*)&s_imf[r * 260 + ch * 8 + 4];
            h[0] = (_Float16)a.x;  h[1] = (_Float16)a.y;
            h[2] = (_Float16)a.z;  h[3] = (_Float16)a.w;
            h[4] = (_Float16)bb.x; h[5] = (_Float16)bb.y;
            h[6] = (_Float16)bb.z; h[7] = (_Float16)bb.w;
        } else {
#pragma unroll
            for (int k = 0; k < 8; ++k) h[k] = (_Float16)0.f;
        }
        *(f16x8*)&imh[r * 256 + ch * 8] = h;
    }

    // sh f16 [32][256], word-masked
    const int sl = s_l[b];
    _Float16* sh = (_Float16*)(ws + WS_SH) + (size_t)b * NW * 256;
    const float4* s4 = (const float4*)(s + (size_t)b * NW * ND);
    for (int i = t; i < NW * 32; i += 256) {
        int w = i >> 5, ch = i & 31;
        f16x8 h;
        if (w < sl) {
            const float4 a  = s4[w * 64 + ch * 2];
            const float4 bb = s4[w * 64 + ch * 2 + 1];
            h[0] = (_Float16)a.x;  h[1] = (_Float16)a.y;
            h[2] = (_Float16)a.z;  h[3] = (_Float16)a.w;
            h[4] = (_Float16)bb.x; h[5] = (_Float16)bb.y;
            h[6] = (_Float16)bb.z; h[7] = (_Float16)bb.w;
        } else {
#pragma unroll
            for (int k = 0; k < 8; ++k) h[k] = (_Float16)0.f;
        }
        *(f16x8*)&sh[w * 256 + ch * 8] = h;
    }

    // n1[b][w]
    {
        const int w = t >> 3, g = t & 7;
        float acc = 0.f;
        for (int j = 0; j < 8; ++j) {
            float4 v = s4[w * 64 + g * 8 + j];
            acc += v.x * v.x + v.y * v.y + v.z * v.z + v.w * v.w;
        }
        acc += __shfl_down(acc, 4, 8);
        acc += __shfl_down(acc, 2, 8);
        acc += __shfl_down(acc, 1, 8);
        if (g == 0) ws[WS_N1 + b * NW + w] = sqrtf(acc);
    }
}

// =====================================================================
// fused: pipelined A0 register-GEMM + leaky/norm/softmax + n2 MFMA
// block = (image b, 8 captions = 256 cols); grid (16, 128)
// =====================================================================
__global__ __launch_bounds__(256, 4) void fused_kernel(
    const int* __restrict__ s_l, const float* __restrict__ im_mask,
    float* __restrict__ ws)
{
    const int n0 = blockIdx.x * 256;
    const int b  = blockIdx.y;
    const int t  = threadIdx.x;
    const int wave = t >> 6, lane = t & 63;
    const int lm = lane & 15, kg = lane >> 4;

    // one shared buffer: first raw A0 tile [36][264] f16, later E tile [256][72]
    __shared__ _Float16 s_buf[256 * 72];   // 36,864 B
    __shared__ float s_coef[288];
    __shared__ float s_n2[256];
    __shared__ float s_m[NR];
    __shared__ int   s_sl[8];
    _Float16* s_rawh = s_buf;
    _Float16* s_E    = s_buf;

    const _Float16* imh = (const _Float16*)(ws + WS_IMH) + (size_t)b * 48 * 256;
    const _Float16* sh  = (const _Float16*)(ws + WS_SH);
    const _Float16* Gg  = (const _Float16*)(ws + WS_GH) + (size_t)b * GH_ELEMS;

    const float n1v = ws[WS_N1 + n0 + t];
    if (t < NR) s_m[t] = im_mask[b * NR + t];
    if (t < 8)  s_sl[t] = s_l[(n0 >> 5) + t];

    // ---- phase 1: A0 tile 48x256, K=256, double-buffered fragment pipeline ----
    f32x4 acc[3][4];
#pragma unroll
    for (int mt = 0; mt < 3; ++mt)
#pragma unroll
        for (int nt = 0; nt < 4; ++nt) acc[mt][nt] = (f32x4){0.f, 0.f, 0.f, 0.f};

    const _Float16* aBase = imh + lm * 256 + kg * 8;
    const _Float16* bBase = sh + (size_t)(n0 + wave * 64 + lm) * 256 + kg * 8;

    f16x8 ab[2][3], bb[2][4];
#pragma unroll
    for (int mt = 0; mt < 3; ++mt) ab[0][mt] = *(const f16x8*)(aBase + mt * 4096);
#pragma unroll
    for (int nt = 0; nt < 4; ++nt) bb[0][nt] = *(const f16x8*)(bBase + nt * 4096);

#pragma unroll
    for (int ks = 0; ks < 8; ++ks) {
        const int cur = ks & 1, nxt = cur ^ 1;
        if (ks < 7) {
#pragma unroll
            for (int mt = 0; mt < 3; ++mt)
                ab[nxt][mt] = *(const f16x8*)(aBase + mt * 4096 + (ks + 1) * 32);
#pragma unroll
            for (int nt = 0; nt < 4; ++nt)
                bb[nxt][nt] = *(const f16x8*)(bBase + nt * 4096 + (ks + 1) * 32);
        }
#pragma unroll
        for (int mt = 0; mt < 3; ++mt)
#pragma unroll
            for (int nt = 0; nt < 4; ++nt)
                acc[mt][nt] = __builtin_amdgcn_mfma_f32_16x16x32_f16(ab[cur][mt], bb[cur][nt], acc[mt][nt], 0, 0, 0);
    }

    // ---- phase 2: acc -> raw tile [r][264] f16 (r<36) ----
#pragma unroll
    for (int mt = 0; mt < 3; ++mt) {
#pragma unroll
        for (int nt = 0; nt < 4; ++nt) {
#pragma unroll
            for (int v = 0; v < 4; ++v) {
                const int r = mt * 16 + kg * 4 + v;
                if (r < NR)
                    s_rawh[r * 264 + wave * 64 + nt * 16 + lm] = (_Float16)acc[mt][nt][v];
            }
        }
    }
    __syncthreads();

    // ---- preload own column into registers (raw dies after coef pass) ----
    float rawf[NR];
#pragma unroll
    for (int r = 0; r < NR; ++r) rawf[r] = (float)s_rawh[r * 264 + t];

    // ---- coef pass: per (r, caption): LAM / (||X||_w + eps) ----
    for (int i = t; i < NR * 8; i += 256) {
        const int r = i >> 3, p = i & 7;
        const float one_m = 1.f - s_m[r];
        float ss = 0.f;
        const _Float16* row = &s_rawh[r * 264 + p * 32];
#pragma unroll
        for (int j = 0; j < 4; ++j) {
            f16x8 h = *(const f16x8*)(row + 8 * j);
#pragma unroll
            for (int k2 = 0; k2 < 8; ++k2) {
                float raw = (float)h[k2];
                float X = (raw >= 0.f ? raw : 0.1f * raw) + one_m;
                ss += X * X;
            }
        }
        s_coef[i] = LAMf / (sqrtf(ss) + EPSf);
    }
    __syncthreads();   // raw fully consumed; E may overwrite buffer

    // ---- prefetch G fragments for n2-MFMA (consumed after next barrier) ----
    f16x8 gf[2][3];
#pragma unroll
    for (int ks = 0; ks < 2; ++ks)
#pragma unroll
        for (int rt = 0; rt < 3; ++rt)
            gf[ks][rt] = *(const f16x8*)(Gg + (rt * 16 + lm) * 72 + ks * 32 + kg * 8);

    // ---- pass B: E = exp(X*coef)*m (den/w12 in regs), write E [n][72] ----
    float den = 0.f, W = 0.f;
    {
        const int p = t >> 5;
#pragma unroll
        for (int r4 = 0; r4 < 9; ++r4) {
            f16x4 pk;
#pragma unroll
            for (int j = 0; j < 4; ++j) {
                const int r = r4 * 4 + j;
                float raw = rawf[r];
                float mm = s_m[r];
                float X = (raw >= 0.f ? raw : 0.1f * raw) + (1.f - mm);
                float E = __expf(X * s_coef[r * 8 + p]) * mm;
                den += E;
                W += E * raw;
                pk[j] = (_Float16)E;
            }
            *(f16x4*)&s_E[t * 72 + r4 * 4] = pk;
        }
        f16x4 z4; z4[0] = z4[1] = z4[2] = z4[3] = (_Float16)0.f;
#pragma unroll
        for (int j = 9; j < 16; ++j) *(f16x4*)&s_E[t * 72 + 4 * j] = z4;
    }
    __syncthreads();

    // ---- n2 MFMA: D[n][r'] = sum_k E[n][k] G[r'][k] (K=64), n2 = sum D*E ----
    {
        f32x4 d[4][3];
#pragma unroll
        for (int tt = 0; tt < 4; ++tt)
#pragma unroll
            for (int rt = 0; rt < 3; ++rt) d[tt][rt] = (f32x4){0.f, 0.f, 0.f, 0.f};
#pragma unroll
        for (int ks = 0; ks < 2; ++ks) {
            f16x8 af[4];
#pragma unroll
            for (int tt = 0; tt < 4; ++tt)
                af[tt] = *(const f16x8*)&s_E[(wave * 64 + tt * 16 + lm) * 72 + ks * 32 + kg * 8];
#pragma unroll
            for (int tt = 0; tt < 4; ++tt)
#pragma unroll
                for (int rt = 0; rt < 3; ++rt)
                    d[tt][rt] = __builtin_amdgcn_mfma_f32_16x16x32_f16(af[tt], gf[ks][rt], d[tt][rt], 0, 0, 0);
        }
#pragma unroll
        for (int tt = 0; tt < 4; ++tt) {
#pragma unroll
            for (int v = 0; v < 4; ++v) {
                const int n = wave * 64 + tt * 16 + kg * 4 + v;
                float p2 = 0.f;
#pragma unroll
                for (int rt = 0; rt < 3; ++rt)
                    p2 += d[tt][rt][v] * (float)s_E[n * 72 + rt * 16 + lm];
                p2 += __shfl_xor(p2, 1, 16);
                p2 += __shfl_xor(p2, 2, 16);
                p2 += __shfl_xor(p2, 4, 16);
                p2 += __shfl_xor(p2, 8, 16);
                if (lm == 0) s_n2[n] = p2;
            }
        }
    }
    __syncthreads();

    // ---- final: cos (softmax denominators cancel), caption-sum, score ----
    {
        const int w = t & 31, p = t >> 5;
        const float n2 = fmaxf(s_n2[t], 0.f);
        const float cosv = W / fmaxf(n1v * sqrtf(n2), EPSf * den);
        const int sl = s_sl[p];
        float val = (w < sl) ? cosv : 0.f;
        val += __shfl_xor(val, 1, 32);
        val += __shfl_xor(val, 2, 32);
        val += __shfl_xor(val, 4, 32);
        val += __shfl_xor(val, 8, 32);
        val += __shfl_xor(val, 16, 32);
        if (w == 0) ws[WS_SCORES + b * NB + (n0 >> 5) + p] = val / (float)sl;
    }
}

// =====================================================================
// FALLBACK PATH (used only if ws_size too small)
// =====================================================================
__global__ __launch_bounds__(256) void prep_fb_kernel(
    const float* __restrict__ im, const float* __restrict__ s,
    float* __restrict__ ws)
{
    const int b = blockIdx.x;
    const int t = threadIdx.x;
    __shared__ float s_imf[NR * 260];

    const float4* im4 = (const float4*)(im + (size_t)b * NR * ND);
    for (int i = t; i < NR * (ND / 4); i += 256) {
        int r = i >> 6, c4 = i & 63;
        *(float4*)&s_imf[r * 260 + 4 * c4] = im4[i];
    }
    __syncthreads();

    float* G = ws + FB_WS_G + (size_t)b * NR * G_STRIDE;
    for (int i = t; i < NR * NR; i += 256) {
        int r = i / NR, rp = i - r * NR;
        const float4* a  = (const float4*)&s_imf[r * 260];
        const float4* bb = (const float4*)&s_imf[rp * 260];
        float acc = 0.f;
        for (int k = 0; k < ND / 4; ++k) {
            float4 x = a[k], y = bb[k];
            acc += x.x * y.x + x.y * y.y + x.z * y.z + x.w * y.w;
        }
        G[r * G_STRIDE + rp] = acc;
    }

    const int w = t >> 3, g = t & 7;
    const float4* s4 = (const float4*)(s + (size_t)b * NW * ND);
    float acc = 0.f;
    for (int j = 0; j < 8; ++j) {
        float4 v = s4[w * 64 + g * 8 + j];
        acc += v.x * v.x + v.y * v.y + v.z * v.z + v.w * v.w;
    }
    acc += __shfl_down(acc, 4, 8);
    acc += __shfl_down(acc, 2, 8);
    acc += __shfl_down(acc, 1, 8);
    if (g == 0) ws[FB_WS_N1 + b * NW + w] = sqrtf(acc);
}

__global__ __launch_bounds__(384) void scores_fb_kernel(
    const float* __restrict__ im, const float* __restrict__ s,
    const int* __restrict__ s_l, const float* __restrict__ im_mask,
    float* __restrict__ ws)
{
    const int c = blockIdx.x;
    const int b = blockIdx.y;
    const int t = threadIdx.x;

    __shared__ _Float16 s_imh[48 * HS];
    __shared__ _Float16 s_caph[NW * HS];
    __shared__ float s_A0[NR * 33];
    __shared__ float s_X[NR * 33];
    __shared__ float s_y[NW * 40];
    __shared__ float s_Gf[NR * G_STRIDE];
    __shared__ float s_nrm[NR];
    __shared__ float s_m[NR];
    __shared__ float s_p1[NW * 12];
    __shared__ float s_p2[NW * 12];

    const int sl = s_l[c];

    const float4* im4 = (const float4*)(im + (size_t)b * NR * ND);
    for (int i = t; i < NR * 32; i += 384) {
        int r = i >> 5, ch = i & 31;
        float4 a  = im4[r * 64 + ch * 2];
        float4 bb = im4[r * 64 + ch * 2 + 1];
        f16x8 h;
        h[0] = (_Float16)a.x;  h[1] = (_Float16)a.y;
        h[2] = (_Float16)a.z;  h[3] = (_Float16)a.w;
        h[4] = (_Float16)bb.x; h[5] = (_Float16)bb.y;
        h[6] = (_Float16)bb.z; h[7] = (_Float16)bb.w;
        *(f16x8*)&s_imh[r * HS + ch * 8] = h;
    }
    {
        unsigned int* z = (unsigned int*)&s_imh[NR * HS];
        for (int i = t; i < 12 * (HS / 2); i += 384) z[i] = 0u;
    }
    const float4* s4 = (const float4*)(s + (size_t)c * NW * ND);
    for (int i = t; i < NW * 32; i += 384) {
        int w = i >> 5, ch = i & 31;
        f16x8 h;
        if (w < sl) {
            float4 a  = s4[w * 64 + ch * 2];
            float4 bb = s4[w * 64 + ch * 2 + 1];
            h[0] = (_Float16)a.x;  h[1] = (_Float16)a.y;
            h[2] = (_Float16)a.z;  h[3] = (_Float16)a.w;
            h[4] = (_Float16)bb.x; h[5] = (_Float16)bb.y;
            h[6] = (_Float16)bb.z; h[7] = (_Float16)bb.w;
        } else {
#pragma unroll
            for (int k = 0; k < 8; ++k) h[k] = (_Float16)0.f;
        }
        *(f16x8*)&s_caph[w * HS + ch * 8] = h;
    }
    {
        const float4* Gg = (const float4*)(ws + FB_WS_G + (size_t)b * NR * G_STRIDE);
        float4* Gs = (float4*)s_Gf;
        for (int i = t; i < NR * 9; i += 384) {
            int r = i / 9, q = i - r * 9;
            Gs[r * 10 + q] = Gg[r * 10 + q];
        }
    }
    if (t < NR) s_m[t] = im_mask[b * NR + t];
    __syncthreads();

    {
        const int wave = t >> 6, lane = t & 63;
        const int r0 = (wave >> 1) * 16, w0 = (wave & 1) * 16;
        const int m = lane & 15, kg = lane >> 4;
        f32x4 acc = {0.f, 0.f, 0.f, 0.f};
        const _Float16* ap = &s_imh[(r0 + m) * HS + kg * 8];
        const _Float16* bp = &s_caph[(w0 + m) * HS + kg * 8];
#pragma unroll
        for (int ks = 0; ks < 8; ++ks) {
            f16x8 av = *(const f16x8*)(ap + ks * 32);
            f16x8 bv = *(const f16x8*)(bp + ks * 32);
            acc = __builtin_amdgcn_mfma_f32_16x16x32_f16(av, bv, acc, 0, 0, 0);
        }
        const int wcol = w0 + m;
        const int rbase = r0 + kg * 4;
#pragma unroll
        for (int v = 0; v < 4; ++v) {
            int r = rbase + v;
            if (r < NR) {
                float rawv = acc[v];
                s_A0[r * 33 + wcol] = rawv;
                float lk = rawv >= 0.f ? rawv : 0.1f * rawv;
                s_X[r * 33 + wcol] = lk + (1.f - s_m[r]);
            }
        }
    }
    __syncthreads();

    if (t < NR) {
        float sum = 0.f;
        for (int w = 0; w < NW; ++w) { float x = s_X[t * 33 + w]; sum += x * x; }
        s_nrm[t] = sqrtf(sum) + EPSf;
    }
    __syncthreads();

    if (t < NW) {
        float xs[NR];
        float mx = -1e30f;
#pragma unroll
        for (int r = 0; r < NR; ++r) {
            float a = s_X[r * 33 + t] / s_nrm[r] * s_m[r] * LAMf;
            xs[r] = a; mx = fmaxf(mx, a);
        }
        float sum = 0.f;
#pragma unroll
        for (int r = 0; r < NR; ++r) {
            float e = __expf(xs[r] - mx) * s_m[r];
            xs[r] = e; sum += e;
        }
        float inv = 1.f / sum;
#pragma unroll
        for (int r = 0; r < NR; ++r) s_y[t * 40 + r] = xs[r] * inv;
    }
    __syncthreads();

    if (t < 288) {
        const int w = t / 9, q = t - (t / 9) * 9;
        float4 y4 = *(const float4*)&s_y[w * 40 + q * 4];
        float4 acc4 = {0.f, 0.f, 0.f, 0.f};
        float w12p = 0.f;
#pragma unroll
        for (int r = 0; r < NR; ++r) {
            float yr = s_y[w * 40 + r];
            float4 g4 = *(const float4*)&s_Gf[r * G_STRIDE + q * 4];
            acc4.x += yr * g4.x; acc4.y += yr * g4.y;
            acc4.z += yr * g4.z; acc4.w += yr * g4.w;
        }
        float n2p = acc4.x * y4.x + acc4.y * y4.y + acc4.z * y4.z + acc4.w * y4.w;
#pragma unroll
        for (int k = 0; k < 4; ++k) {
            int r = q * 4 + k;
            w12p += s_y[w * 40 + r] * s_A0[r * 33 + w];
        }
        s_p1[w * 12 + q] = w12p;
        s_p2[w * 12 + q] = n2p;
    }
    __syncthreads();

    if (t < NW) {
        float w12v = 0.f, n2v = 0.f;
        for (int q = 0; q < 9; ++q) { w12v += s_p1[t * 12 + q]; n2v += s_p2[t * 12 + q]; }
        float n1v = ws[FB_WS_N1 + c * NW + t];
        float cosv = w12v / fmaxf(n1v * sqrtf(n2v), EPSf);
        float val = (t < sl) ? cosv : 0.f;
#pragma unroll
        for (int k = 16; k; k >>= 1) val += __shfl_down(val, k, 32);
        if (t == 0) ws[WS_SCORES + b * NB + c] = val / (float)sl;
    }
}

// ---------------- contrastive loss over 128x128 scores ----------------
__global__ __launch_bounds__(128) void loss_kernel(
    const float* __restrict__ scores, const int* __restrict__ qid,
    float* __restrict__ out)
{
    __shared__ int   s_q[NB];
    __shared__ float s_c[NB];
    __shared__ float s_v[NB];
    const int i = threadIdx.x;
    s_q[i] = qid[i];
    __syncthreads();

    const int q = s_q[i];
    bool dup = false;
    for (int j = 0; j < i; ++j) dup = dup || (s_q[j] == q);

    const float* row = scores + i * NB;
    float mx = -1e30f;
    for (int j = 0; j < NB; ++j) {
        float l = (row[j] - ((j == i) ? MARGINf : 0.f)) * TEMPf;
        mx = fmaxf(mx, l);
    }
    float sum = 0.f;
    for (int j = 0; j < NB; ++j) {
        float l = (row[j] - ((j == i) ? MARGINf : 0.f)) * TEMPf;
        sum += expf(l - mx);
    }
    const float logZ = mx + logf(sum);
    const float picked = (row[i] - MARGINf) * TEMPf;
    const float valid = dup ? 0.f : 1.f;
    s_c[i] = (logZ - picked) * valid;
    s_v[i] = valid;
    __syncthreads();
    if (i == 0) {
        float a = 0.f, v = 0.f;
        for (int j = 0; j < NB; ++j) { a += s_c[j]; v += s_v[j]; }
        out[0] = a / fmaxf(v, 1.f);
    }
}

extern "C" void kernel_launch(void* const* d_in, const int* in_sizes, int n_in,
                              void* d_out, int out_size, void* d_ws, size_t ws_size,
                              hipStream_t stream) {
    const float* im      = (const float*)d_in[0];
    const float* s       = (const float*)d_in[1];
    const int*   s_l     = (const int*)d_in[2];
    const float* im_mask = (const float*)d_in[3];
    const int*   qid     = (const int*)d_in[4];

    float* ws  = (float*)d_ws;
    float* out = (float*)d_out;

    if (ws_size >= WS_NEED_BYTES) {
        prep3_kernel<<<NB, 256, 0, stream>>>(im, s, s_l, ws);
        fused_kernel<<<dim3(16, NB), 256, 0, stream>>>(s_l, im_mask, ws);
    } else {
        prep_fb_kernel<<<NB, 256, 0, stream>>>(im, s, ws);
        dim3 grid(NB, NB);
        scores_fb_kernel<<<grid, 384, 0, stream>>>(im, s, s_l, im_mask, ws);
    }
    loss_kernel<<<1, 128, 0, stream>>>(ws + WS_SCORES, qid, out);
}

// Round 8
// 199.164 us; speedup vs baseline: 1.0029x; 1.0029x over previous
//
#include <hip/hip_runtime.h>
#include <hip/hip_bf16.h>
#include <math.h>

#define NB 128   // batch
#define NR 36    // regions
#define NW 32    // words
#define ND 256   // feature dim

#define MARGINf 0.05f
#define TEMPf   14.0f
#define LAMf    9.0f
#define EPSf    1e-8f

typedef _Float16 f16x8 __attribute__((ext_vector_type(8)));
typedef _Float16 f16x4 __attribute__((ext_vector_type(4)));
typedef float    f32x4 __attribute__((ext_vector_type(4)));

// ================= workspace layout (float offsets) =================
#define WS_SCORES 0
#define WS_N1     16384
#define WS_GH     20480                  // f16[128][48*72] rows/cols >=36 zero
#define GH_ELEMS  (48 * 72)              // 3456 f16 per image
#define WS_IMH    241664                 // f16[128][48][256], rows 36..47 zero
#define WS_SH     1028096                // f16[128][32][256], word-masked

// =====================================================================
// prep3: f16 conversions (imh zero-padded, sh word-masked), Gram f16, n1
// =====================================================================
__global__ __launch_bounds__(256) void prep3_kernel(
    const float* __restrict__ im, const float* __restrict__ s,
    const int* __restrict__ s_l, float* __restrict__ ws)
{
    const int b = blockIdx.x;
    const int t = threadIdx.x;
    __shared__ float s_imf[NR * 260];

    const float4* im4 = (const float4*)(im + (size_t)b * NR * ND);
    for (int i = t; i < NR * 64; i += 256) {
        int r = i >> 6, c4 = i & 63;
        *(float4*)&s_imf[r * 260 + 4 * c4] = im4[i];
    }
    // zero G region
    unsigned int* Gz = (unsigned int*)((_Float16*)(ws + WS_GH) + (size_t)b * GH_ELEMS);
    for (int i = t; i < GH_ELEMS / 2; i += 256) Gz[i] = 0u;
    __syncthreads();

    // Gram f16 [48][72], fill 36x36
    _Float16* Gh = (_Float16*)(ws + WS_GH) + (size_t)b * GH_ELEMS;
    for (int i = t; i < NR * NR; i += 256) {
        int r = i / NR, rp = i - r * NR;
        const float4* a  = (const float4*)&s_imf[r * 260];
        const float4* bb = (const float4*)&s_imf[rp * 260];
        float acc = 0.f;
        for (int k = 0; k < 64; ++k) {
            float4 x = a[k], y = bb[k];
            acc += x.x * y.x + x.y * y.y + x.z * y.z + x.w * y.w;
        }
        Gh[r * 72 + rp] = (_Float16)acc;
    }

    // imh f16 [48][256], rows 36..47 zero
    _Float16* imh = (_Float16*)(ws + WS_IMH) + (size_t)b * 48 * 256;
    for (int i = t; i < 48 * 32; i += 256) {
        int r = i >> 5, ch = i & 31;
        f16x8 h;
        if (r < NR) {
            const float4 a  = *(const float4*)&s_imf[r * 260 + ch * 8];
            const float4 bb = *(const float4*)&s_imf[r * 260 + ch * 8 + 4];
            h[0] = (_Float16)a.x;  h[1] = (_Float16)a.y;
            h[2] = (_Float16)a.z;  h[3] = (_Float16)a.w;
            h[4] = (_Float16)bb.x; h[5] = (_Float16)bb.y;
            h[6] = (_Float16)bb.z; h[7] = (_Float16)bb.w;
        } else {
#pragma unroll
            for (int k = 0; k < 8; ++k) h[k] = (_Float16)0.f;
        }
        *(f16x8*)&imh[r * 256 + ch * 8] = h;
    }

    // sh f16 [32][256], word-masked
    const int sl = s_l[b];
    _Float16* sh = (_Float16*)(ws + WS_SH) + (size_t)b * NW * 256;
    const float4* s4 = (const float4*)(s + (size_t)b * NW * ND);
    for (int i = t; i < NW * 32; i += 256) {
        int w = i >> 5, ch = i & 31;
        f16x8 h;
        if (w < sl) {
            const float4 a  = s4[w * 64 + ch * 2];
            const float4 bb = s4[w * 64 + ch * 2 + 1];
            h[0] = (_Float16)a.x;  h[1] = (_Float16)a.y;
            h[2] = (_Float16)a.z;  h[3] = (_Float16)a.w;
            h[4] = (_Float16)bb.x; h[5] = (_Float16)bb.y;
            h[6] = (_Float16)bb.z; h[7] = (_Float16)bb.w;
        } else {
#pragma unroll
            for (int k = 0; k < 8; ++k) h[k] = (_Float16)0.f;
        }
        *(f16x8*)&sh[w * 256 + ch * 8] = h;
    }

    // n1[b][w]
    {
        const int w = t >> 3, g = t & 7;
        float acc = 0.f;
        for (int j = 0; j < 8; ++j) {
            float4 v = s4[w * 64 + g * 8 + j];
            acc += v.x * v.x + v.y * v.y + v.z * v.z + v.w * v.w;
        }
        acc += __shfl_down(acc, 4, 8);
        acc += __shfl_down(acc, 2, 8);
        acc += __shfl_down(acc, 1, 8);
        if (g == 0) ws[WS_N1 + b * NW + w] = sqrtf(acc);
    }
}

// =====================================================================
// wavefused: ONE WAVE per (image b, caption c). No __syncthreads at all.
// grid (32, 128), block 256 = 4 independent waves.
// =====================================================================
__global__ __launch_bounds__(256, 4) void wavefused_kernel(
    const int* __restrict__ s_l, const float* __restrict__ im_mask,
    float* __restrict__ ws)
{
    const int t = threadIdx.x;
    const int wv = t >> 6, lane = t & 63;
    const int lm = lane & 15, kg = lane >> 4;
    const int b = blockIdx.y;
    const int c = blockIdx.x * 4 + wv;

    __shared__ _Float16 sE[4][32 * 72];   // per-wave E tile [w][k], k padded to 72
    __shared__ float sN2[4][32];

    const _Float16* imh = (const _Float16*)(ws + WS_IMH) + (size_t)b * 48 * 256;
    const _Float16* shc = (const _Float16*)(ws + WS_SH) + (size_t)c * 32 * 256;
    const _Float16* Gg  = (const _Float16*)(ws + WS_GH) + (size_t)b * GH_ELEMS;

    // early loads (consumed after phase 1)
    float n1v[2];
#pragma unroll
    for (int nt = 0; nt < 2; ++nt)
        n1v[nt] = ws[WS_N1 + c * NW + nt * 16 + lm];

    float mr[12];
#pragma unroll
    for (int mt = 0; mt < 3; ++mt)
#pragma unroll
        for (int v = 0; v < 4; ++v) {
            const int r = mt * 16 + kg * 4 + v;
            const float mv = im_mask[b * NR + (r < NR ? r : NR - 1)];
            mr[mt * 4 + v] = (r < NR) ? mv : 0.f;
        }
    const int sl = s_l[c];

    // ---- phase 1: A0 tile 48(r) x 32(w) in registers, K=256, dbuf ----
    f32x4 acc[3][2];
#pragma unroll
    for (int mt = 0; mt < 3; ++mt)
#pragma unroll
        for (int nt = 0; nt < 2; ++nt) acc[mt][nt] = (f32x4){0.f, 0.f, 0.f, 0.f};

    const _Float16* aB = imh + lm * 256 + kg * 8;
    const _Float16* bB = shc + lm * 256 + kg * 8;

    f16x8 ab[2][3], bb[2][2];
#pragma unroll
    for (int mt = 0; mt < 3; ++mt) ab[0][mt] = *(const f16x8*)(aB + mt * 4096);
#pragma unroll
    for (int nt = 0; nt < 2; ++nt) bb[0][nt] = *(const f16x8*)(bB + nt * 4096);

#pragma unroll
    for (int ks = 0; ks < 8; ++ks) {
        const int cur = ks & 1, nxt = cur ^ 1;
        if (ks < 7) {
#pragma unroll
            for (int mt = 0; mt < 3; ++mt)
                ab[nxt][mt] = *(const f16x8*)(aB + mt * 4096 + (ks + 1) * 32);
#pragma unroll
            for (int nt = 0; nt < 2; ++nt)
                bb[nxt][nt] = *(const f16x8*)(bB + nt * 4096 + (ks + 1) * 32);
        }
#pragma unroll
        for (int mt = 0; mt < 3; ++mt)
#pragma unroll
            for (int nt = 0; nt < 2; ++nt)
                acc[mt][nt] = __builtin_amdgcn_mfma_f32_16x16x32_f16(ab[cur][mt], bb[cur][nt], acc[mt][nt], 0, 0, 0);
    }
    // lane holds raw[r][w]: r = mt*16 + kg*4 + v, w = nt*16 + lm

    // ---- norm over w (all 32 cols) -> coef[r] per lane's 12 rows ----
    float coef[12];
#pragma unroll
    for (int mt = 0; mt < 3; ++mt)
#pragma unroll
        for (int v = 0; v < 4; ++v) {
            const int idx = mt * 4 + v;
            const float one_m = 1.f - mr[idx];
            float p = 0.f;
#pragma unroll
            for (int nt = 0; nt < 2; ++nt) {
                const float raw = acc[mt][nt][v];
                const float X = (raw >= 0.f ? raw : 0.1f * raw) + one_m;
                p += X * X;
            }
            p += __shfl_xor(p, 1);
            p += __shfl_xor(p, 2);
            p += __shfl_xor(p, 4);
            p += __shfl_xor(p, 8);
            coef[idx] = LAMf / (sqrtf(p) + EPSf);
        }

    // ---- E = exp(X*coef)*m; den, W per col; E -> per-wave LDS [w][72] ----
    float den[2] = {0.f, 0.f}, Wv[2] = {0.f, 0.f};
#pragma unroll
    for (int nt = 0; nt < 2; ++nt) {
        const int w = nt * 16 + lm;
#pragma unroll
        for (int mt = 0; mt < 3; ++mt) {
            f16x4 pk;
#pragma unroll
            for (int v = 0; v < 4; ++v) {
                const int idx = mt * 4 + v;
                const float raw = acc[mt][nt][v];
                const float X = (raw >= 0.f ? raw : 0.1f * raw) + (1.f - mr[idx]);
                const float E = __expf(X * coef[idx]) * mr[idx];
                den[nt] += E;
                Wv[nt] += E * raw;
                pk[v] = (_Float16)E;
            }
            *(f16x4*)&sE[wv][w * 72 + mt * 16 + kg * 4] = pk;
        }
        // zero K-pad k = 48..63
        f16x4 z4; z4[0] = z4[1] = z4[2] = z4[3] = (_Float16)0.f;
        *(f16x4*)&sE[wv][w * 72 + 48 + kg * 4] = z4;
    }
    // reduce den/W over kg (rows split across kg)
#pragma unroll
    for (int nt = 0; nt < 2; ++nt) {
        den[nt] += __shfl_xor(den[nt], 16);
        den[nt] += __shfl_xor(den[nt], 32);
        Wv[nt]  += __shfl_xor(Wv[nt], 16);
        Wv[nt]  += __shfl_xor(Wv[nt], 32);
    }

    // ---- n2: D[w][r'] = sum_k E[w][k] G[r'][k] (K=64), n2 = sum_r' D*E ----
    {
        f32x4 d[2][3];
#pragma unroll
        for (int wt = 0; wt < 2; ++wt)
#pragma unroll
            for (int rt = 0; rt < 3; ++rt) d[wt][rt] = (f32x4){0.f, 0.f, 0.f, 0.f};
#pragma unroll
        for (int ks = 0; ks < 2; ++ks) {
            f16x8 af[2], gf[3];
#pragma unroll
            for (int wt = 0; wt < 2; ++wt)
                af[wt] = *(const f16x8*)&sE[wv][(wt * 16 + lm) * 72 + ks * 32 + kg * 8];
#pragma unroll
            for (int rt = 0; rt < 3; ++rt)
                gf[rt] = *(const f16x8*)(Gg + (rt * 16 + lm) * 72 + ks * 32 + kg * 8);
#pragma unroll
            for (int wt = 0; wt < 2; ++wt)
#pragma unroll
                for (int rt = 0; rt < 3; ++rt)
                    d[wt][rt] = __builtin_amdgcn_mfma_f32_16x16x32_f16(af[wt], gf[rt], d[wt][rt], 0, 0, 0);
        }
#pragma unroll
        for (int wt = 0; wt < 2; ++wt) {
#pragma unroll
            for (int v = 0; v < 4; ++v) {
                const int w = wt * 16 + kg * 4 + v;
                float p2 = 0.f;
#pragma unroll
                for (int rt = 0; rt < 3; ++rt)
                    p2 += d[wt][rt][v] * (float)sE[wv][w * 72 + rt * 16 + lm];
                p2 += __shfl_xor(p2, 1);
                p2 += __shfl_xor(p2, 2);
                p2 += __shfl_xor(p2, 4);
                p2 += __shfl_xor(p2, 8);
                if (lm == 0) sN2[wv][w] = p2;
            }
        }
    }

    // ---- final: cos (softmax denominators cancel), sum over words ----
    {
        float tot = 0.f;
#pragma unroll
        for (int nt = 0; nt < 2; ++nt) {
            const int w = nt * 16 + lm;
            const float n2 = fmaxf(sN2[wv][w], 0.f);
            const float cosv = Wv[nt] / fmaxf(n1v[nt] * sqrtf(n2), EPSf * den[nt]);
            tot += (w < sl) ? cosv : 0.f;
        }
        tot += __shfl_xor(tot, 1);
        tot += __shfl_xor(tot, 2);
        tot += __shfl_xor(tot, 4);
        tot += __shfl_xor(tot, 8);
        if (lane == 0) ws[WS_SCORES + b * NB + c] = tot / (float)sl;
    }
}

// ---------------- contrastive loss over 128x128 scores ----------------
__global__ __launch_bounds__(128) void loss_kernel(
    const float* __restrict__ scores, const int* __restrict__ qid,
    float* __restrict__ out)
{
    __shared__ int   s_q[NB];
    __shared__ float s_c[NB];
    __shared__ float s_v[NB];
    const int i = threadIdx.x;
    s_q[i] = qid[i];
    __syncthreads();

    const int q = s_q[i];
    bool dup = false;
    for (int j = 0; j < i; ++j) dup = dup || (s_q[j] == q);

    const float* row = scores + i * NB;
    float mx = -1e30f;
    for (int j = 0; j < NB; ++j) {
        float l = (row[j] - ((j == i) ? MARGINf : 0.f)) * TEMPf;
        mx = fmaxf(mx, l);
    }
    float sum = 0.f;
    for (int j = 0; j < NB; ++j) {
        float l = (row[j] - ((j == i) ? MARGINf : 0.f)) * TEMPf;
        sum += expf(l - mx);
    }
    const float logZ = mx + logf(sum);
    const float picked = (row[i] - MARGINf) * TEMPf;
    const float valid = dup ? 0.f : 1.f;
    s_c[i] = (logZ - picked) * valid;
    s_v[i] = valid;
    __syncthreads();
    if (i == 0) {
        float a = 0.f, v = 0.f;
        for (int j = 0; j < NB; ++j) { a += s_c[j]; v += s_v[j]; }
        out[0] = a / fmaxf(v, 1.f);
    }
}

extern "C" void kernel_launch(void* const* d_in, const int* in_sizes, int n_in,
                              void* d_out, int out_size, void* d_ws, size_t ws_size,
                              hipStream_t stream) {
    const float* im      = (const float*)d_in[0];
    const float* s       = (const float*)d_in[1];
    const int*   s_l     = (const int*)d_in[2];
    const float* im_mask = (const float*)d_in[3];
    const int*   qid     = (const int*)d_in[4];

    float* ws  = (float*)d_ws;
    float* out = (float*)d_out;

    prep3_kernel<<<NB, 256, 0, stream>>>(im, s, s_l, ws);
    wavefused_kernel<<<dim3(32, NB), 256, 0, stream>>>(s_l, im_mask, ws);
    loss_kernel<<<1, 128, 0, stream>>>(ws + WS_SCORES, qid, out);
}

// Round 9
// 176.017 us; speedup vs baseline: 1.1348x; 1.1315x over previous
//
#include <hip/hip_runtime.h>
#include <hip/hip_bf16.h>
#include <math.h>

#define NB 128   // batch
#define NR 36    // regions
#define NW 32    // words
#define ND 256   // feature dim

#define MARGINf 0.05f
#define TEMPf   14.0f
#define LAMf    9.0f
#define EPSf    1e-8f

typedef _Float16 f16x8 __attribute__((ext_vector_type(8)));
typedef _Float16 f16x4 __attribute__((ext_vector_type(4)));
typedef float    f32x4 __attribute__((ext_vector_type(4)));

// ================= workspace layout (float offsets) =================
#define WS_SCORES 0
#define WS_N1     16384
#define WS_GH     20480                  // f16[128][48*72] rows/cols >=36 zero
#define GH_ELEMS  (48 * 72)              // 3456 f16 per image
#define WS_IMH    241664                 // f16[128][48][256], rows 36..47 zero
#define WS_SH     1028096                // f16[128][32][256], word-masked

// =====================================================================
// prep3: f16 conversions (imh zero-padded, sh word-masked), Gram f16, n1
// =====================================================================
__global__ __launch_bounds__(256) void prep3_kernel(
    const float* __restrict__ im, const float* __restrict__ s,
    const int* __restrict__ s_l, float* __restrict__ ws)
{
    const int b = blockIdx.x;
    const int t = threadIdx.x;
    __shared__ float s_imf[NR * 260];

    const float4* im4 = (const float4*)(im + (size_t)b * NR * ND);
    for (int i = t; i < NR * 64; i += 256) {
        int r = i >> 6, c4 = i & 63;
        *(float4*)&s_imf[r * 260 + 4 * c4] = im4[i];
    }
    // zero G region
    unsigned int* Gz = (unsigned int*)((_Float16*)(ws + WS_GH) + (size_t)b * GH_ELEMS);
    for (int i = t; i < GH_ELEMS / 2; i += 256) Gz[i] = 0u;
    __syncthreads();

    // Gram f16 [48][72], fill 36x36
    _Float16* Gh = (_Float16*)(ws + WS_GH) + (size_t)b * GH_ELEMS;
    for (int i = t; i < NR * NR; i += 256) {
        int r = i / NR, rp = i - r * NR;
        const float4* a  = (const float4*)&s_imf[r * 260];
        const float4* bb = (const float4*)&s_imf[rp * 260];
        float acc = 0.f;
        for (int k = 0; k < 64; ++k) {
            float4 x = a[k], y = bb[k];
            acc += x.x * y.x + x.y * y.y + x.z * y.z + x.w * y.w;
        }
        Gh[r * 72 + rp] = (_Float16)acc;
    }

    // imh f16 [48][256], rows 36..47 zero
    _Float16* imh = (_Float16*)(ws + WS_IMH) + (size_t)b * 48 * 256;
    for (int i = t; i < 48 * 32; i += 256) {
        int r = i >> 5, ch = i & 31;
        f16x8 h;
        if (r < NR) {
            const float4 a  = *(const float4*)&s_imf[r * 260 + ch * 8];
            const float4 bb = *(const float4*)&s_imf[r * 260 + ch * 8 + 4];
            h[0] = (_Float16)a.x;  h[1] = (_Float16)a.y;
            h[2] = (_Float16)a.z;  h[3] = (_Float16)a.w;
            h[4] = (_Float16)bb.x; h[5] = (_Float16)bb.y;
            h[6] = (_Float16)bb.z; h[7] = (_Float16)bb.w;
        } else {
#pragma unroll
            for (int k = 0; k < 8; ++k) h[k] = (_Float16)0.f;
        }
        *(f16x8*)&imh[r * 256 + ch * 8] = h;
    }

    // sh f16 [32][256], word-masked
    const int sl = s_l[b];
    _Float16* sh = (_Float16*)(ws + WS_SH) + (size_t)b * NW * 256;
    const float4* s4 = (const float4*)(s + (size_t)b * NW * ND);
    for (int i = t; i < NW * 32; i += 256) {
        int w = i >> 5, ch = i & 31;
        f16x8 h;
        if (w < sl) {
            const float4 a  = s4[w * 64 + ch * 2];
            const float4 bb = s4[w * 64 + ch * 2 + 1];
            h[0] = (_Float16)a.x;  h[1] = (_Float16)a.y;
            h[2] = (_Float16)a.z;  h[3] = (_Float16)a.w;
            h[4] = (_Float16)bb.x; h[5] = (_Float16)bb.y;
            h[6] = (_Float16)bb.z; h[7] = (_Float16)bb.w;
        } else {
#pragma unroll
            for (int k = 0; k < 8; ++k) h[k] = (_Float16)0.f;
        }
        *(f16x8*)&sh[w * 256 + ch * 8] = h;
    }

    // n1[b][w]
    {
        const int w = t >> 3, g = t & 7;
        float acc = 0.f;
        for (int j = 0; j < 8; ++j) {
            float4 v = s4[w * 64 + g * 8 + j];
            acc += v.x * v.x + v.y * v.y + v.z * v.z + v.w * v.w;
        }
        acc += __shfl_down(acc, 4, 8);
        acc += __shfl_down(acc, 2, 8);
        acc += __shfl_down(acc, 1, 8);
        if (g == 0) ws[WS_N1 + b * NW + w] = sqrtf(acc);
    }
}

// =====================================================================
// fusedv2: LDS-staged A0 GEMM + intra-wave glue.
// block = (image b, 4 captions); 256 thr = 4 waves; wave <-> caption.
// LDS: sA 48x136h + sB 128x136h (E tiles reuse sB after phase 1).
// =====================================================================
#define AS 136   // halves per A-tile row (K-half 128 + 8 pad)
#define BS 136

__global__ __launch_bounds__(256, 3) void fusedv2_kernel(
    const int* __restrict__ s_l, const float* __restrict__ im_mask,
    float* __restrict__ ws)
{
    const int t = threadIdx.x;
    const int wv = t >> 6, lane = t & 63;
    const int lm = lane & 15, kg = lane >> 4;
    const int b  = blockIdx.y;
    const int c0 = blockIdx.x * 4;
    const int c  = c0 + wv;

    __shared__ _Float16 sA[48 * AS];     // 13,056 B
    __shared__ _Float16 sB[128 * BS];    // 34,816 B (E tiles reuse this)
    __shared__ float sN2[4][32];

    const _Float16* imh = (const _Float16*)(ws + WS_IMH) + (size_t)b * 48 * 256;
    const _Float16* shg = (const _Float16*)(ws + WS_SH) + (size_t)c0 * 32 * 256;
    const _Float16* Gg  = (const _Float16*)(ws + WS_GH) + (size_t)b * GH_ELEMS;

    // small early loads
    float n1v[2];
#pragma unroll
    for (int nt = 0; nt < 2; ++nt)
        n1v[nt] = ws[WS_N1 + c * NW + nt * 16 + lm];
    float mr[12];
#pragma unroll
    for (int mt = 0; mt < 3; ++mt)
#pragma unroll
        for (int v = 0; v < 4; ++v) {
            const int r = mt * 16 + kg * 4 + v;
            const float mv = im_mask[b * NR + (r < NR ? r : NR - 1)];
            mr[mt * 4 + v] = (r < NR) ? mv : 0.f;
        }
    const int sl = s_l[c];

    // ---- phase 1: A0 tile 48(r) x 128(n) via LDS-staged MFMA, K=2x128 ----
    f32x4 acc[3][2];
#pragma unroll
    for (int mt = 0; mt < 3; ++mt)
#pragma unroll
        for (int nt = 0; nt < 2; ++nt) acc[mt][nt] = (f32x4){0.f, 0.f, 0.f, 0.f};

    for (int kh = 0; kh < 2; ++kh) {
        // stage A half: 48 rows x 16 chunks of 16B, fully coalesced
        for (int i = t; i < 48 * 16; i += 256) {
            const int r = i >> 4, ch = i & 15;
            *(f16x8*)&sA[r * AS + ch * 8] =
                *(const f16x8*)(imh + r * 256 + kh * 128 + ch * 8);
        }
        // stage B half: 128 rows (4 captions x 32 words) x 16 chunks
        for (int i = t; i < 128 * 16; i += 256) {
            const int n = i >> 4, ch = i & 15;
            *(f16x8*)&sB[n * BS + ch * 8] =
                *(const f16x8*)(shg + (size_t)n * 256 + kh * 128 + ch * 8);
        }
        __syncthreads();
#pragma unroll
        for (int ks = 0; ks < 4; ++ks) {
            f16x8 af[3], bf[2];
#pragma unroll
            for (int mt = 0; mt < 3; ++mt)
                af[mt] = *(const f16x8*)&sA[(mt * 16 + lm) * AS + ks * 32 + kg * 8];
#pragma unroll
            for (int nt = 0; nt < 2; ++nt)
                bf[nt] = *(const f16x8*)&sB[(wv * 32 + nt * 16 + lm) * BS + ks * 32 + kg * 8];
#pragma unroll
            for (int mt = 0; mt < 3; ++mt)
#pragma unroll
                for (int nt = 0; nt < 2; ++nt)
                    acc[mt][nt] = __builtin_amdgcn_mfma_f32_16x16x32_f16(af[mt], bf[nt], acc[mt][nt], 0, 0, 0);
        }
        __syncthreads();   // final one also guards E-overwrite of sB
    }
    // lane holds raw[r][w]: r = mt*16 + kg*4 + v, w = nt*16 + lm

    // ---- G fragment prefetch from global (overlaps with glue VALU) ----
    f16x8 gf[2][3];
#pragma unroll
    for (int ks = 0; ks < 2; ++ks)
#pragma unroll
        for (int rt = 0; rt < 3; ++rt)
            gf[ks][rt] = *(const f16x8*)(Gg + (rt * 16 + lm) * 72 + ks * 32 + kg * 8);

    // ---- norm over w -> coef[r] per lane's 12 rows ----
    float coef[12];
#pragma unroll
    for (int mt = 0; mt < 3; ++mt)
#pragma unroll
        for (int v = 0; v < 4; ++v) {
            const int idx = mt * 4 + v;
            const float one_m = 1.f - mr[idx];
            float p = 0.f;
#pragma unroll
            for (int nt = 0; nt < 2; ++nt) {
                const float raw = acc[mt][nt][v];
                const float X = (raw >= 0.f ? raw : 0.1f * raw) + one_m;
                p += X * X;
            }
            p += __shfl_xor(p, 1);
            p += __shfl_xor(p, 2);
            p += __shfl_xor(p, 4);
            p += __shfl_xor(p, 8);
            coef[idx] = LAMf / (sqrtf(p) + EPSf);
        }

    // ---- E = exp(X*coef)*m; den, W per col; E -> own region in sB [w][72] ----
    _Float16* sE = &sB[wv * 32 * 72];
    float den[2] = {0.f, 0.f}, Wv[2] = {0.f, 0.f};
#pragma unroll
    for (int nt = 0; nt < 2; ++nt) {
        const int w = nt * 16 + lm;
#pragma unroll
        for (int mt = 0; mt < 3; ++mt) {
            f16x4 pk;
#pragma unroll
            for (int v = 0; v < 4; ++v) {
                const int idx = mt * 4 + v;
                const float raw = acc[mt][nt][v];
                const float X = (raw >= 0.f ? raw : 0.1f * raw) + (1.f - mr[idx]);
                const float E = __expf(X * coef[idx]) * mr[idx];
                den[nt] += E;
                Wv[nt] += E * raw;
                pk[v] = (_Float16)E;
            }
            *(f16x4*)&sE[w * 72 + mt * 16 + kg * 4] = pk;
        }
        // zero K-pad k = 48..63
        f16x4 z4; z4[0] = z4[1] = z4[2] = z4[3] = (_Float16)0.f;
        *(f16x4*)&sE[w * 72 + 48 + kg * 4] = z4;
    }
    // reduce den/W over kg (rows split across kg)
#pragma unroll
    for (int nt = 0; nt < 2; ++nt) {
        den[nt] += __shfl_xor(den[nt], 16);
        den[nt] += __shfl_xor(den[nt], 32);
        Wv[nt]  += __shfl_xor(Wv[nt], 16);
        Wv[nt]  += __shfl_xor(Wv[nt], 32);
    }

    // ---- n2: D[w][r'] = sum_k E[w][k] G[r'][k] (K=64), n2 = sum_r' D*E ----
    {
        f32x4 d[2][3];
#pragma unroll
        for (int wt = 0; wt < 2; ++wt)
#pragma unroll
            for (int rt = 0; rt < 3; ++rt) d[wt][rt] = (f32x4){0.f, 0.f, 0.f, 0.f};
#pragma unroll
        for (int ks = 0; ks < 2; ++ks) {
            f16x8 af[2];
#pragma unroll
            for (int wt = 0; wt < 2; ++wt)
                af[wt] = *(const f16x8*)&sE[(wt * 16 + lm) * 72 + ks * 32 + kg * 8];
#pragma unroll
            for (int wt = 0; wt < 2; ++wt)
#pragma unroll
                for (int rt = 0; rt < 3; ++rt)
                    d[wt][rt] = __builtin_amdgcn_mfma_f32_16x16x32_f16(af[wt], gf[ks][rt], d[wt][rt], 0, 0, 0);
        }
#pragma unroll
        for (int wt = 0; wt < 2; ++wt) {
#pragma unroll
            for (int v = 0; v < 4; ++v) {
                const int w = wt * 16 + kg * 4 + v;
                float p2 = 0.f;
#pragma unroll
                for (int rt = 0; rt < 3; ++rt)
                    p2 += d[wt][rt][v] * (float)sE[w * 72 + rt * 16 + lm];
                p2 += __shfl_xor(p2, 1);
                p2 += __shfl_xor(p2, 2);
                p2 += __shfl_xor(p2, 4);
                p2 += __shfl_xor(p2, 8);
                if (lm == 0) sN2[wv][w] = p2;
            }
        }
    }

    // ---- final: cos (softmax denominators cancel), sum over words ----
    {
        float tot = 0.f;
#pragma unroll
        for (int nt = 0; nt < 2; ++nt) {
            const int w = nt * 16 + lm;
            const float n2 = fmaxf(sN2[wv][w], 0.f);
            const float cosv = Wv[nt] / fmaxf(n1v[nt] * sqrtf(n2), EPSf * den[nt]);
            tot += (w < sl) ? cosv : 0.f;
        }
        tot += __shfl_xor(tot, 1);
        tot += __shfl_xor(tot, 2);
        tot += __shfl_xor(tot, 4);
        tot += __shfl_xor(tot, 8);
        if (lane == 0) ws[WS_SCORES + b * NB + c] = tot / (float)sl;
    }
}

// ---------------- contrastive loss over 128x128 scores ----------------
__global__ __launch_bounds__(128) void loss_kernel(
    const float* __restrict__ scores, const int* __restrict__ qid,
    float* __restrict__ out)
{
    __shared__ int   s_q[NB];
    __shared__ float s_c[NB];
    __shared__ float s_v[NB];
    const int i = threadIdx.x;
    s_q[i] = qid[i];
    __syncthreads();

    const int q = s_q[i];
    bool dup = false;
    for (int j = 0; j < i; ++j) dup = dup || (s_q[j] == q);

    const float* row = scores + i * NB;
    float mx = -1e30f;
    for (int j = 0; j < NB; ++j) {
        float l = (row[j] - ((j == i) ? MARGINf : 0.f)) * TEMPf;
        mx = fmaxf(mx, l);
    }
    float sum = 0.f;
    for (int j = 0; j < NB; ++j) {
        float l = (row[j] - ((j == i) ? MARGINf : 0.f)) * TEMPf;
        sum += expf(l - mx);
    }
    const float logZ = mx + logf(sum);
    const float picked = (row[i] - MARGINf) * TEMPf;
    const float valid = dup ? 0.f : 1.f;
    s_c[i] = (logZ - picked) * valid;
    s_v[i] = valid;
    __syncthreads();
    if (i == 0) {
        float a = 0.f, v = 0.f;
        for (int j = 0; j < NB; ++j) { a += s_c[j]; v += s_v[j]; }
        out[0] = a / fmaxf(v, 1.f);
    }
}

extern "C" void kernel_launch(void* const* d_in, const int* in_sizes, int n_in,
                              void* d_out, int out_size, void* d_ws, size_t ws_size,
                              hipStream_t stream) {
    const float* im      = (const float*)d_in[0];
    const float* s       = (const float*)d_in[1];
    const int*   s_l     = (const int*)d_in[2];
    const float* im_mask = (const float*)d_in[3];
    const int*   qid     = (const int*)d_in[4];

    float* ws  = (float*)d_ws;
    float* out = (float*)d_out;

    prep3_kernel<<<NB, 256, 0, stream>>>(im, s, s_l, ws);
    fusedv2_kernel<<<dim3(32, NB), 256, 0, stream>>>(s_l, im_mask, ws);
    loss_kernel<<<1, 128, 0, stream>>>(ws + WS_SCORES, qid, out);
}

// Round 10
// 170.133 us; speedup vs baseline: 1.1740x; 1.0346x over previous
//
#include <hip/hip_runtime.h>
#include <hip/hip_bf16.h>
#include <math.h>

#define NB 128   // batch
#define NR 36    // regions
#define NW 32    // words
#define ND 256   // feature dim

#define MARGINf 0.05f
#define TEMPf   14.0f
#define LAMf    9.0f
#define EPSf    1e-8f

typedef _Float16 f16x8 __attribute__((ext_vector_type(8)));
typedef _Float16 f16x4 __attribute__((ext_vector_type(4)));
typedef float    f32x4 __attribute__((ext_vector_type(4)));

// ================= workspace layout (float offsets) =================
#define WS_SCORES 0
#define WS_N1     16384
#define WS_GH     20480                  // f16[128][48*72] rows/cols >=36 zero
#define GH_ELEMS  (48 * 72)              // 3456 f16 per image
#define WS_IMH    241664                 // f16[128][48][256], rows 36..47 zero
#define WS_SH     1028096                // f16[128][32][256], word-masked

// =====================================================================
// prep3: f16 conversions (imh zero-padded, sh word-masked), Gram f16, n1
// =====================================================================
__global__ __launch_bounds__(256) void prep3_kernel(
    const float* __restrict__ im, const float* __restrict__ s,
    const int* __restrict__ s_l, float* __restrict__ ws)
{
    const int b = blockIdx.x;
    const int t = threadIdx.x;
    __shared__ float s_imf[NR * 260];

    const float4* im4 = (const float4*)(im + (size_t)b * NR * ND);
    for (int i = t; i < NR * 64; i += 256) {
        int r = i >> 6, c4 = i & 63;
        *(float4*)&s_imf[r * 260 + 4 * c4] = im4[i];
    }
    // zero G region
    unsigned int* Gz = (unsigned int*)((_Float16*)(ws + WS_GH) + (size_t)b * GH_ELEMS);
    for (int i = t; i < GH_ELEMS / 2; i += 256) Gz[i] = 0u;
    __syncthreads();

    // Gram f16 [48][72], fill 36x36
    _Float16* Gh = (_Float16*)(ws + WS_GH) + (size_t)b * GH_ELEMS;
    for (int i = t; i < NR * NR; i += 256) {
        int r = i / NR, rp = i - r * NR;
        const float4* a  = (const float4*)&s_imf[r * 260];
        const float4* bb = (const float4*)&s_imf[rp * 260];
        float acc = 0.f;
        for (int k = 0; k < 64; ++k) {
            float4 x = a[k], y = bb[k];
            acc += x.x * y.x + x.y * y.y + x.z * y.z + x.w * y.w;
        }
        Gh[r * 72 + rp] = (_Float16)acc;
    }

    // imh f16 [48][256], rows 36..47 zero
    _Float16* imh = (_Float16*)(ws + WS_IMH) + (size_t)b * 48 * 256;
    for (int i = t; i < 48 * 32; i += 256) {
        int r = i >> 5, ch = i & 31;
        f16x8 h;
        if (r < NR) {
            const float4 a  = *(const float4*)&s_imf[r * 260 + ch * 8];
            const float4 bb = *(const float4*)&s_imf[r * 260 + ch * 8 + 4];
            h[0] = (_Float16)a.x;  h[1] = (_Float16)a.y;
            h[2] = (_Float16)a.z;  h[3] = (_Float16)a.w;
            h[4] = (_Float16)bb.x; h[5] = (_Float16)bb.y;
            h[6] = (_Float16)bb.z; h[7] = (_Float16)bb.w;
        } else {
#pragma unroll
            for (int k = 0; k < 8; ++k) h[k] = (_Float16)0.f;
        }
        *(f16x8*)&imh[r * 256 + ch * 8] = h;
    }

    // sh f16 [32][256], word-masked
    const int sl = s_l[b];
    _Float16* sh = (_Float16*)(ws + WS_SH) + (size_t)b * NW * 256;
    const float4* s4 = (const float4*)(s + (size_t)b * NW * ND);
    for (int i = t; i < NW * 32; i += 256) {
        int w = i >> 5, ch = i & 31;
        f16x8 h;
        if (w < sl) {
            const float4 a  = s4[w * 64 + ch * 2];
            const float4 bb = s4[w * 64 + ch * 2 + 1];
            h[0] = (_Float16)a.x;  h[1] = (_Float16)a.y;
            h[2] = (_Float16)a.z;  h[3] = (_Float16)a.w;
            h[4] = (_Float16)bb.x; h[5] = (_Float16)bb.y;
            h[6] = (_Float16)bb.z; h[7] = (_Float16)bb.w;
        } else {
#pragma unroll
            for (int k = 0; k < 8; ++k) h[k] = (_Float16)0.f;
        }
        *(f16x8*)&sh[w * 256 + ch * 8] = h;
    }

    // n1[b][w]
    {
        const int w = t >> 3, g = t & 7;
        float acc = 0.f;
        for (int j = 0; j < 8; ++j) {
            float4 v = s4[w * 64 + g * 8 + j];
            acc += v.x * v.x + v.y * v.y + v.z * v.z + v.w * v.w;
        }
        acc += __shfl_down(acc, 4, 8);
        acc += __shfl_down(acc, 2, 8);
        acc += __shfl_down(acc, 1, 8);
        if (g == 0) ws[WS_N1 + b * NW + w] = sqrtf(acc);
    }
}

// =====================================================================
// fusedv3: low-LDS K-quarter staged GEMM + intra-wave glue.
// block = (image b, 4 captions); 256 thr = 4 waves; wave <-> caption.
// LDS ~25.4 KB -> 6 blocks/CU target.
// =====================================================================
#define QS 72    // halves per LDS row (K-quarter 64 + 8 pad)

__global__ __launch_bounds__(256, 5) void fusedv3_kernel(
    const int* __restrict__ s_l, const float* __restrict__ im_mask,
    float* __restrict__ ws)
{
    const int t = threadIdx.x;
    const int wv = t >> 6, lane = t & 63;
    const int lm = lane & 15, kg = lane >> 4;
    const int b  = blockIdx.y;
    const int c0 = blockIdx.x * 4;
    const int c  = c0 + wv;

    __shared__ _Float16 sA[48 * QS];     // 6,912 B
    __shared__ _Float16 sB[128 * QS];    // 18,432 B (E tiles reuse this)
    __shared__ float sN2[4][32];         // 512 B
    __shared__ float s_mask[48];         // 192 B

    const _Float16* imh = (const _Float16*)(ws + WS_IMH) + (size_t)b * 48 * 256;
    const _Float16* shg = (const _Float16*)(ws + WS_SH) + (size_t)c0 * 32 * 256;
    const _Float16* Gg  = (const _Float16*)(ws + WS_GH) + (size_t)b * GH_ELEMS;

    // small early loads
    float n1v[2];
#pragma unroll
    for (int nt = 0; nt < 2; ++nt)
        n1v[nt] = ws[WS_N1 + c * NW + nt * 16 + lm];
    const int sl = s_l[c];
    if (t < 48) s_mask[t] = (t < NR) ? im_mask[b * NR + t] : 0.f;

    // ---- phase 1: A0 tile 48(r) x 128(n), K = 4 x 64, single-buffer LDS ----
    f32x4 acc[3][2];
#pragma unroll
    for (int mt = 0; mt < 3; ++mt)
#pragma unroll
        for (int nt = 0; nt < 2; ++nt) acc[mt][nt] = (f32x4){0.f, 0.f, 0.f, 0.f};

    for (int kq = 0; kq < 4; ++kq) {
        if (kq) __syncthreads();     // MFMA of prev quarter done before restage
        // stage A quarter: 48 rows x 8 chunks of 16B
        for (int i = t; i < 384; i += 256) {
            const int r = i >> 3, ch = i & 7;
            *(f16x8*)&sA[r * QS + ch * 8] =
                *(const f16x8*)(imh + r * 256 + kq * 64 + ch * 8);
        }
        // stage B quarter: 128 rows (4 captions x 32 words) x 8 chunks
        for (int i = t; i < 1024; i += 256) {
            const int n = i >> 3, ch = i & 7;
            *(f16x8*)&sB[n * QS + ch * 8] =
                *(const f16x8*)(shg + (size_t)n * 256 + kq * 64 + ch * 8);
        }
        __syncthreads();
#pragma unroll
        for (int ks = 0; ks < 2; ++ks) {
            f16x8 af[3], bf[2];
#pragma unroll
            for (int mt = 0; mt < 3; ++mt)
                af[mt] = *(const f16x8*)&sA[(mt * 16 + lm) * QS + ks * 32 + kg * 8];
#pragma unroll
            for (int nt = 0; nt < 2; ++nt)
                bf[nt] = *(const f16x8*)&sB[(wv * 32 + nt * 16 + lm) * QS + ks * 32 + kg * 8];
#pragma unroll
            for (int mt = 0; mt < 3; ++mt)
#pragma unroll
                for (int nt = 0; nt < 2; ++nt)
                    acc[mt][nt] = __builtin_amdgcn_mfma_f32_16x16x32_f16(af[mt], bf[nt], acc[mt][nt], 0, 0, 0);
        }
    }
    // lane holds raw[r][w]: r = mt*16 + kg*4 + v, w = nt*16 + lm
    // NOTE: no barrier needed after last quarter — each wave's E region in sB
    // coincides exactly with its own caption's rows (intra-wave WAR, in-order).

    // ---- G fragment prefetch from global (overlaps glue VALU) ----
    f16x8 gf[2][3];
#pragma unroll
    for (int ks = 0; ks < 2; ++ks)
#pragma unroll
        for (int rt = 0; rt < 3; ++rt)
            gf[ks][rt] = *(const f16x8*)(Gg + (rt * 16 + lm) * 72 + ks * 32 + kg * 8);

    // ---- region masks from LDS ----
    float mr[12];
#pragma unroll
    for (int mt = 0; mt < 3; ++mt)
#pragma unroll
        for (int v = 0; v < 4; ++v)
            mr[mt * 4 + v] = s_mask[mt * 16 + kg * 4 + v];

    // ---- norm over w -> coef[r] per lane's 12 rows ----
    float coef[12];
#pragma unroll
    for (int mt = 0; mt < 3; ++mt)
#pragma unroll
        for (int v = 0; v < 4; ++v) {
            const int idx = mt * 4 + v;
            const float one_m = 1.f - mr[idx];
            float p = 0.f;
#pragma unroll
            for (int nt = 0; nt < 2; ++nt) {
                const float raw = acc[mt][nt][v];
                const float X = (raw >= 0.f ? raw : 0.1f * raw) + one_m;
                p += X * X;
            }
            p += __shfl_xor(p, 1);
            p += __shfl_xor(p, 2);
            p += __shfl_xor(p, 4);
            p += __shfl_xor(p, 8);
            coef[idx] = LAMf / (sqrtf(p) + EPSf);
        }

    // ---- E = exp(X*coef)*m; den, W per col; E -> own caption rows of sB ----
    _Float16* sE = &sB[wv * 32 * QS];
    float den[2] = {0.f, 0.f}, Wv[2] = {0.f, 0.f};
#pragma unroll
    for (int nt = 0; nt < 2; ++nt) {
        const int w = nt * 16 + lm;
#pragma unroll
        for (int mt = 0; mt < 3; ++mt) {
            f16x4 pk;
#pragma unroll
            for (int v = 0; v < 4; ++v) {
                const int idx = mt * 4 + v;
                const float raw = acc[mt][nt][v];
                const float X = (raw >= 0.f ? raw : 0.1f * raw) + (1.f - mr[idx]);
                const float E = __expf(X * coef[idx]) * mr[idx];
                den[nt] += E;
                Wv[nt] += E * raw;
                pk[v] = (_Float16)E;
            }
            *(f16x4*)&sE[w * QS + mt * 16 + kg * 4] = pk;
        }
        // zero K-pad k = 48..63
        f16x4 z4; z4[0] = z4[1] = z4[2] = z4[3] = (_Float16)0.f;
        *(f16x4*)&sE[w * QS + 48 + kg * 4] = z4;
    }
    // reduce den/W over kg (rows split across kg)
#pragma unroll
    for (int nt = 0; nt < 2; ++nt) {
        den[nt] += __shfl_xor(den[nt], 16);
        den[nt] += __shfl_xor(den[nt], 32);
        Wv[nt]  += __shfl_xor(Wv[nt], 16);
        Wv[nt]  += __shfl_xor(Wv[nt], 32);
    }

    // ---- n2: D[w][r'] = sum_k E[w][k] G[r'][k] (K=64), n2 = sum_r' D*E ----
    {
        f32x4 d[2][3];
#pragma unroll
        for (int wt = 0; wt < 2; ++wt)
#pragma unroll
            for (int rt = 0; rt < 3; ++rt) d[wt][rt] = (f32x4){0.f, 0.f, 0.f, 0.f};
#pragma unroll
        for (int ks = 0; ks < 2; ++ks) {
            f16x8 af[2];
#pragma unroll
            for (int wt = 0; wt < 2; ++wt)
                af[wt] = *(const f16x8*)&sE[(wt * 16 + lm) * QS + ks * 32 + kg * 8];
#pragma unroll
            for (int wt = 0; wt < 2; ++wt)
#pragma unroll
                for (int rt = 0; rt < 3; ++rt)
                    d[wt][rt] = __builtin_amdgcn_mfma_f32_16x16x32_f16(af[wt], gf[ks][rt], d[wt][rt], 0, 0, 0);
        }
#pragma unroll
        for (int wt = 0; wt < 2; ++wt) {
#pragma unroll
            for (int v = 0; v < 4; ++v) {
                const int w = wt * 16 + kg * 4 + v;
                float p2 = 0.f;
#pragma unroll
                for (int rt = 0; rt < 3; ++rt)
                    p2 += d[wt][rt][v] * (float)sE[w * QS + rt * 16 + lm];
                p2 += __shfl_xor(p2, 1);
                p2 += __shfl_xor(p2, 2);
                p2 += __shfl_xor(p2, 4);
                p2 += __shfl_xor(p2, 8);
                if (lm == 0) sN2[wv][w] = p2;
            }
        }
    }

    // ---- final: cos (softmax denominators cancel), sum over words ----
    {
        float tot = 0.f;
#pragma unroll
        for (int nt = 0; nt < 2; ++nt) {
            const int w = nt * 16 + lm;
            const float n2 = fmaxf(sN2[wv][w], 0.f);
            const float cosv = Wv[nt] / fmaxf(n1v[nt] * sqrtf(n2), EPSf * den[nt]);
            tot += (w < sl) ? cosv : 0.f;
        }
        tot += __shfl_xor(tot, 1);
        tot += __shfl_xor(tot, 2);
        tot += __shfl_xor(tot, 4);
        tot += __shfl_xor(tot, 8);
        if (lane == 0) ws[WS_SCORES + b * NB + c] = tot / (float)sl;
    }
}

// ---------------- contrastive loss over 128x128 scores ----------------
__global__ __launch_bounds__(128) void loss_kernel(
    const float* __restrict__ scores, const int* __restrict__ qid,
    float* __restrict__ out)
{
    __shared__ int   s_q[NB];
    __shared__ float s_c[NB];
    __shared__ float s_v[NB];
    const int i = threadIdx.x;
    s_q[i] = qid[i];
    __syncthreads();

    const int q = s_q[i];
    bool dup = false;
    for (int j = 0; j < i; ++j) dup = dup || (s_q[j] == q);

    const float* row = scores + i * NB;
    float mx = -1e30f;
    for (int j = 0; j < NB; ++j) {
        float l = (row[j] - ((j == i) ? MARGINf : 0.f)) * TEMPf;
        mx = fmaxf(mx, l);
    }
    float sum = 0.f;
    for (int j = 0; j < NB; ++j) {
        float l = (row[j] - ((j == i) ? MARGINf : 0.f)) * TEMPf;
        sum += expf(l - mx);
    }
    const float logZ = mx + logf(sum);
    const float picked = (row[i] - MARGINf) * TEMPf;
    const float valid = dup ? 0.f : 1.f;
    s_c[i] = (logZ - picked) * valid;
    s_v[i] = valid;
    __syncthreads();
    if (i == 0) {
        float a = 0.f, v = 0.f;
        for (int j = 0; j < NB; ++j) { a += s_c[j]; v += s_v[j]; }
        out[0] = a / fmaxf(v, 1.f);
    }
}

extern "C" void kernel_launch(void* const* d_in, const int* in_sizes, int n_in,
                              void* d_out, int out_size, void* d_ws, size_t ws_size,
                              hipStream_t stream) {
    const float* im      = (const float*)d_in[0];
    const float* s       = (const float*)d_in[1];
    const int*   s_l     = (const int*)d_in[2];
    const float* im_mask = (const float*)d_in[3];
    const int*   qid     = (const int*)d_in[4];

    float* ws  = (float*)d_ws;
    float* out = (float*)d_out;

    prep3_kernel<<<NB, 256, 0, stream>>>(im, s, s_l, ws);
    fusedv3_kernel<<<dim3(32, NB), 256, 0, stream>>>(s_l, im_mask, ws);
    loss_kernel<<<1, 128, 0, stream>>>(ws + WS_SCORES, qid, out);
}

// Round 11
// 162.828 us; speedup vs baseline: 1.2267x; 1.0449x over previous
//
#include <hip/hip_runtime.h>
#include <hip/hip_bf16.h>
#include <math.h>

#define NB 128   // batch
#define NR 36    // regions
#define NW 32    // words
#define ND 256   // feature dim

#define MARGINf 0.05f
#define TEMPf   14.0f
#define LAMf    9.0f
#define EPSf    1e-8f

typedef _Float16 f16x8 __attribute__((ext_vector_type(8)));
typedef _Float16 f16x4 __attribute__((ext_vector_type(4)));
typedef float    f32x4 __attribute__((ext_vector_type(4)));

// ================= workspace layout (float offsets) =================
// All GEMM operands stored in MFMA-fragment order ("swizzled"):
//   fragment f, lane l, elem j  ->  base + f*512 + l*8 + j   (halves)
// so a wave's f16x8 fragment load = 64 lanes x 16B contiguous = 1KB burst.
#define WS_SCORES 0
#define WS_N1     16384
#define WS_GW     20480                   // f16[128][6*512]   (rt*2+ks frags)
#define GW_H      3072
#define WS_IMW    217088                  // f16[128][24*512]  (mt*8+ks frags)
#define IMW_H     12288
#define WS_SHW    1003520                 // f16[128][16*512]  (nt*8+ks frags)
#define SHW_H     8192

// =====================================================================
// prep4: build swizzled f16 operands (imw, shw word-masked, Gw) + n1
// =====================================================================
__global__ __launch_bounds__(256) void prep4_kernel(
    const float* __restrict__ im, const float* __restrict__ s,
    const int* __restrict__ s_l, float* __restrict__ ws)
{
    const int b = blockIdx.x;
    const int t = threadIdx.x;
    __shared__ float s_imf[NR * 260];
    __shared__ _Float16 s_G[48 * 72];

    const float4* im4 = (const float4*)(im + (size_t)b * NR * ND);
    for (int i = t; i < NR * 64; i += 256) {
        int r = i >> 6, c4 = i & 63;
        *(float4*)&s_imf[r * 260 + 4 * c4] = im4[i];
    }
    // zero G LDS (1728 u32)
    for (int i = t; i < 1728; i += 256) ((unsigned int*)s_G)[i] = 0u;
    __syncthreads();

    // Gram f16 into LDS [48][72], fill 36x36
    for (int i = t; i < NR * NR; i += 256) {
        int r = i / NR, rp = i - r * NR;
        const float4* a  = (const float4*)&s_imf[r * 260];
        const float4* bb = (const float4*)&s_imf[rp * 260];
        float acc = 0.f;
        for (int k = 0; k < 64; ++k) {
            float4 x = a[k], y = bb[k];
            acc += x.x * y.x + x.y * y.y + x.z * y.z + x.w * y.w;
        }
        s_G[r * 72 + rp] = (_Float16)acc;
    }
    __syncthreads();

    // Gw swizzled: 6 fragments (rt*2+ks) x 64 lanes
    _Float16* Gw = (_Float16*)(ws + WS_GW) + (size_t)b * GW_H;
    for (int i = t; i < 6 * 64; i += 256) {
        const int f = i >> 6, l = i & 63;
        const int rt = f >> 1, ks = f & 1;
        const int lm = l & 15, kg = l >> 4;
        f16x8 h = *(const f16x8*)&s_G[(rt * 16 + lm) * 72 + ks * 32 + kg * 8];
        *(f16x8*)((_Float16*)Gw + f * 512 + l * 8) = h;
    }

    // imw swizzled: 24 fragments (mt*8+ks) x 64 lanes, rows >=36 zero
    _Float16* imw = (_Float16*)(ws + WS_IMW) + (size_t)b * IMW_H;
    for (int i = t; i < 24 * 64; i += 256) {
        const int f = i >> 6, l = i & 63;
        const int mt = f >> 3, ks = f & 7;
        const int lm = l & 15, kg = l >> 4;
        const int r = mt * 16 + lm;
        f16x8 h;
        if (r < NR) {
            const int k0 = ks * 32 + kg * 8;
            const float4 a  = *(const float4*)&s_imf[r * 260 + k0];
            const float4 bb = *(const float4*)&s_imf[r * 260 + k0 + 4];
            h[0] = (_Float16)a.x;  h[1] = (_Float16)a.y;
            h[2] = (_Float16)a.z;  h[3] = (_Float16)a.w;
            h[4] = (_Float16)bb.x; h[5] = (_Float16)bb.y;
            h[6] = (_Float16)bb.z; h[7] = (_Float16)bb.w;
        } else {
#pragma unroll
            for (int k = 0; k < 8; ++k) h[k] = (_Float16)0.f;
        }
        *(f16x8*)(imw + f * 512 + l * 8) = h;
    }

    // shw swizzled: 16 fragments (nt*8+ks) x 64 lanes, word-masked
    const int sl = s_l[b];
    _Float16* shw = (_Float16*)(ws + WS_SHW) + (size_t)b * SHW_H;
    const float4* s4 = (const float4*)(s + (size_t)b * NW * ND);
    for (int i = t; i < 16 * 64; i += 256) {
        const int f = i >> 6, l = i & 63;
        const int nt = f >> 3, ks = f & 7;
        const int lm = l & 15, kg = l >> 4;
        const int w = nt * 16 + lm;
        f16x8 h;
        if (w < sl) {
            const int k0 = ks * 32 + kg * 8;     // multiple of 8 floats
            const float4 a  = s4[w * 64 + (k0 >> 2)];
            const float4 bb = s4[w * 64 + (k0 >> 2) + 1];
            h[0] = (_Float16)a.x;  h[1] = (_Float16)a.y;
            h[2] = (_Float16)a.z;  h[3] = (_Float16)a.w;
            h[4] = (_Float16)bb.x; h[5] = (_Float16)bb.y;
            h[6] = (_Float16)bb.z; h[7] = (_Float16)bb.w;
        } else {
#pragma unroll
            for (int k = 0; k < 8; ++k) h[k] = (_Float16)0.f;
        }
        *(f16x8*)(shw + f * 512 + l * 8) = h;
    }

    // n1[b][w]
    {
        const int w = t >> 3, g = t & 7;
        float acc = 0.f;
        for (int j = 0; j < 8; ++j) {
            float4 v = s4[w * 64 + g * 8 + j];
            acc += v.x * v.x + v.y * v.y + v.z * v.z + v.w * v.w;
        }
        acc += __shfl_down(acc, 4, 8);
        acc += __shfl_down(acc, 2, 8);
        acc += __shfl_down(acc, 1, 8);
        if (g == 0) ws[WS_N1 + b * NW + w] = sqrtf(acc);
    }
}

// =====================================================================
// wavefused2: ONE WAVE per (image b, caption c), ZERO barriers.
// All fragment loads coalesced from swizzled operands.
// grid (32, 128), block 256 = 4 independent waves. LDS ~19 KB.
// =====================================================================
__global__ __launch_bounds__(256, 6) void wavefused2_kernel(
    const int* __restrict__ s_l, const float* __restrict__ im_mask,
    float* __restrict__ ws)
{
    const int t = threadIdx.x;
    const int wv = t >> 6, lane = t & 63;
    const int lm = lane & 15, kg = lane >> 4;
    const int b = blockIdx.y;
    const int c = blockIdx.x * 4 + wv;

    __shared__ _Float16 sE[4][32 * 72];   // per-wave E tile [w][k], 4.6 KB each
    __shared__ float sN2[4][32];

    const _Float16* aB = (const _Float16*)(ws + WS_IMW) + (size_t)b * IMW_H + lane * 8;
    const _Float16* bB = (const _Float16*)(ws + WS_SHW) + (size_t)c * SHW_H + lane * 8;
    const _Float16* gB = (const _Float16*)(ws + WS_GW) + (size_t)b * GW_H + lane * 8;

    // early small loads (L1/L2-resident, broadcast-friendly)
    float n1v[2];
#pragma unroll
    for (int nt = 0; nt < 2; ++nt)
        n1v[nt] = ws[WS_N1 + c * NW + nt * 16 + lm];
    float mr[12];
#pragma unroll
    for (int mt = 0; mt < 3; ++mt)
#pragma unroll
        for (int v = 0; v < 4; ++v) {
            const int r = mt * 16 + kg * 4 + v;
            mr[mt * 4 + v] = (r < NR) ? im_mask[b * NR + r] : 0.f;
        }
    const int sl = s_l[c];

    // ---- phase 1: A0 tile 48(r) x 32(w), K=256, coalesced frag loads ----
    f32x4 acc[3][2];
#pragma unroll
    for (int mt = 0; mt < 3; ++mt)
#pragma unroll
        for (int nt = 0; nt < 2; ++nt) acc[mt][nt] = (f32x4){0.f, 0.f, 0.f, 0.f};

    f16x8 af[2][3], bf[2][2];
#pragma unroll
    for (int mt = 0; mt < 3; ++mt) af[0][mt] = *(const f16x8*)(aB + (mt * 8 + 0) * 512);
#pragma unroll
    for (int nt = 0; nt < 2; ++nt) bf[0][nt] = *(const f16x8*)(bB + (nt * 8 + 0) * 512);

#pragma unroll
    for (int ks = 0; ks < 8; ++ks) {
        const int cur = ks & 1, nxt = cur ^ 1;
        if (ks < 7) {
#pragma unroll
            for (int mt = 0; mt < 3; ++mt)
                af[nxt][mt] = *(const f16x8*)(aB + (mt * 8 + ks + 1) * 512);
#pragma unroll
            for (int nt = 0; nt < 2; ++nt)
                bf[nxt][nt] = *(const f16x8*)(bB + (nt * 8 + ks + 1) * 512);
        }
#pragma unroll
        for (int mt = 0; mt < 3; ++mt)
#pragma unroll
            for (int nt = 0; nt < 2; ++nt)
                acc[mt][nt] = __builtin_amdgcn_mfma_f32_16x16x32_f16(af[cur][mt], bf[cur][nt], acc[mt][nt], 0, 0, 0);
    }
    // lane holds raw[r][w]: r = mt*16 + kg*4 + v, w = nt*16 + lm

    // ---- G fragment prefetch (coalesced; overlaps glue VALU) ----
    f16x8 gf[2][3];
#pragma unroll
    for (int ks = 0; ks < 2; ++ks)
#pragma unroll
        for (int rt = 0; rt < 3; ++rt)
            gf[ks][rt] = *(const f16x8*)(gB + (rt * 2 + ks) * 512);

    // ---- norm over w -> coef[r] per lane's 12 rows ----
    float coef[12];
#pragma unroll
    for (int mt = 0; mt < 3; ++mt)
#pragma unroll
        for (int v = 0; v < 4; ++v) {
            const int idx = mt * 4 + v;
            const float one_m = 1.f - mr[idx];
            float p = 0.f;
#pragma unroll
            for (int nt = 0; nt < 2; ++nt) {
                const float raw = acc[mt][nt][v];
                const float X = (raw >= 0.f ? raw : 0.1f * raw) + one_m;
                p += X * X;
            }
            p += __shfl_xor(p, 1);
            p += __shfl_xor(p, 2);
            p += __shfl_xor(p, 4);
            p += __shfl_xor(p, 8);
            coef[idx] = LAMf / (sqrtf(p) + EPSf);
        }

    // ---- E = exp(X*coef)*m; den, W per col; E -> wave-private LDS [w][72] ----
    _Float16* sEw = &sE[wv][0];
    float den[2] = {0.f, 0.f}, Wv[2] = {0.f, 0.f};
#pragma unroll
    for (int nt = 0; nt < 2; ++nt) {
        const int w = nt * 16 + lm;
#pragma unroll
        for (int mt = 0; mt < 3; ++mt) {
            f16x4 pk;
#pragma unroll
            for (int v = 0; v < 4; ++v) {
                const int idx = mt * 4 + v;
                const float raw = acc[mt][nt][v];
                const float X = (raw >= 0.f ? raw : 0.1f * raw) + (1.f - mr[idx]);
                const float E = __expf(X * coef[idx]) * mr[idx];
                den[nt] += E;
                Wv[nt] += E * raw;
                pk[v] = (_Float16)E;
            }
            *(f16x4*)&sEw[w * 72 + mt * 16 + kg * 4] = pk;
        }
        // zero K-pad k = 48..63
        f16x4 z4; z4[0] = z4[1] = z4[2] = z4[3] = (_Float16)0.f;
        *(f16x4*)&sEw[w * 72 + 48 + kg * 4] = z4;
    }
    // reduce den/W over kg (rows split across kg)
#pragma unroll
    for (int nt = 0; nt < 2; ++nt) {
        den[nt] += __shfl_xor(den[nt], 16);
        den[nt] += __shfl_xor(den[nt], 32);
        Wv[nt]  += __shfl_xor(Wv[nt], 16);
        Wv[nt]  += __shfl_xor(Wv[nt], 32);
    }

    // ---- n2: D[w][r'] = sum_k E[w][k] G[r'][k] (K=64), n2 = sum_r' D*E ----
    {
        f32x4 d[2][3];
#pragma unroll
        for (int wt = 0; wt < 2; ++wt)
#pragma unroll
            for (int rt = 0; rt < 3; ++rt) d[wt][rt] = (f32x4){0.f, 0.f, 0.f, 0.f};
#pragma unroll
        for (int ks = 0; ks < 2; ++ks) {
            f16x8 ef[2];
#pragma unroll
            for (int wt = 0; wt < 2; ++wt)
                ef[wt] = *(const f16x8*)&sEw[(wt * 16 + lm) * 72 + ks * 32 + kg * 8];
#pragma unroll
            for (int wt = 0; wt < 2; ++wt)
#pragma unroll
                for (int rt = 0; rt < 3; ++rt)
                    d[wt][rt] = __builtin_amdgcn_mfma_f32_16x16x32_f16(ef[wt], gf[ks][rt], d[wt][rt], 0, 0, 0);
        }
#pragma unroll
        for (int wt = 0; wt < 2; ++wt) {
#pragma unroll
            for (int v = 0; v < 4; ++v) {
                const int w = wt * 16 + kg * 4 + v;
                float p2 = 0.f;
#pragma unroll
                for (int rt = 0; rt < 3; ++rt)
                    p2 += d[wt][rt][v] * (float)sEw[w * 72 + rt * 16 + lm];
                p2 += __shfl_xor(p2, 1);
                p2 += __shfl_xor(p2, 2);
                p2 += __shfl_xor(p2, 4);
                p2 += __shfl_xor(p2, 8);
                if (lm == 0) sN2[wv][w] = p2;
            }
        }
    }

    // ---- final: cos (softmax denominators cancel), sum over words ----
    {
        float tot = 0.f;
#pragma unroll
        for (int nt = 0; nt < 2; ++nt) {
            const int w = nt * 16 + lm;
            const float n2 = fmaxf(sN2[wv][w], 0.f);
            const float cosv = Wv[nt] / fmaxf(n1v[nt] * sqrtf(n2), EPSf * den[nt]);
            tot += (w < sl) ? cosv : 0.f;
        }
        tot += __shfl_xor(tot, 1);
        tot += __shfl_xor(tot, 2);
        tot += __shfl_xor(tot, 4);
        tot += __shfl_xor(tot, 8);
        if (lane == 0) ws[WS_SCORES + b * NB + c] = tot / (float)sl;
    }
}

// ---------------- contrastive loss over 128x128 scores ----------------
__global__ __launch_bounds__(128) void loss_kernel(
    const float* __restrict__ scores, const int* __restrict__ qid,
    float* __restrict__ out)
{
    __shared__ int   s_q[NB];
    __shared__ float s_c[NB];
    __shared__ float s_v[NB];
    const int i = threadIdx.x;
    s_q[i] = qid[i];
    __syncthreads();

    const int q = s_q[i];
    bool dup = false;
    for (int j = 0; j < i; ++j) dup = dup || (s_q[j] == q);

    const float* row = scores + i * NB;
    float mx = -1e30f;
    for (int j = 0; j < NB; ++j) {
        float l = (row[j] - ((j == i) ? MARGINf : 0.f)) * TEMPf;
        mx = fmaxf(mx, l);
    }
    float sum = 0.f;
    for (int j = 0; j < NB; ++j) {
        float l = (row[j] - ((j == i) ? MARGINf : 0.f)) * TEMPf;
        sum += expf(l - mx);
    }
    const float logZ = mx + logf(sum);
    const float picked = (row[i] - MARGINf) * TEMPf;
    const float valid = dup ? 0.f : 1.f;
    s_c[i] = (logZ - picked) * valid;
    s_v[i] = valid;
    __syncthreads();
    if (i == 0) {
        float a = 0.f, v = 0.f;
        for (int j = 0; j < NB; ++j) { a += s_c[j]; v += s_v[j]; }
        out[0] = a / fmaxf(v, 1.f);
    }
}

extern "C" void kernel_launch(void* const* d_in, const int* in_sizes, int n_in,
                              void* d_out, int out_size, void* d_ws, size_t ws_size,
                              hipStream_t stream) {
    const float* im      = (const float*)d_in[0];
    const float* s       = (const float*)d_in[1];
    const int*   s_l     = (const int*)d_in[2];
    const float* im_mask = (const float*)d_in[3];
    const int*   qid     = (const int*)d_in[4];

    float* ws  = (float*)d_ws;
    float* out = (float*)d_out;

    prep4_kernel<<<NB, 256, 0, stream>>>(im, s, s_l, ws);
    wavefused2_kernel<<<dim3(32, NB), 256, 0, stream>>>(s_l, im_mask, ws);
    loss_kernel<<<1, 128, 0, stream>>>(ws + WS_SCORES, qid, out);
}